// Round 8
// baseline (569.064 us; speedup 1.0000x reference)
//
#include <hip/hip_runtime.h>

// NeuralIF GraphNet: 3 layers x (lower GraphNet, upper GraphNet).
// R1: bucketed edge lists + LDS-bin aggregation. R4: no fences in hot path.
// R5: fused aggnode; inline global MLP in edge kernel wave 0.
// R7: one-edge-per-thread edge kernel (VGPR 28) = scalar-weight-stall-bound.
// R8: (a) sorted-domain edges: scatter materializes rows_s/cols_s/attr_s and
// all edge arrays live in bucket-sorted order -> aggnode reads are fully
// coalesced (was 2 random gathers/edge, ~44us each); (b) edge MLP written
// k-outer with float4 weight-row loads + __launch_bounds__(256,3) so
// h[32]+in[18] stay in registers (break the j-outer 18-scalar-load stall).

typedef unsigned int u32;

#define NB_SHIFT 9
#define NB_SIZE 512
#define RSTRIDE 1104  // per-GraphNet region: ebins[64] nbins[64*16] pad

__device__ __forceinline__ float wave_sum(float v) {
#pragma unroll
    for (int off = 32; off > 0; off >>= 1) v += __shfl_down(v, off, 64);
    return v;
}

// ---------------- bucketed-list build (once per call) ----------------

__global__ __launch_bounds__(256) void hist_kernel(
    const int* __restrict__ lr, const int* __restrict__ ur,
    u32* __restrict__ hist, int E, int B) {
    __shared__ u32 h[256];
    const int t = threadIdx.x;
    if (t < B) h[t] = 0;
    __syncthreads();
    const int s = blockIdx.y;
    const int* rows = s ? ur : lr;
    for (int i = blockIdx.x * 256 + t; i < E; i += gridDim.x * 256)
        atomicAdd(&h[rows[i] >> NB_SHIFT], 1u);
    __syncthreads();
    if (t < B && h[t]) atomicAdd(&hist[s * B + t], h[t]);
}

// parallel exclusive scan of both segments (B <= 256), one block
__global__ __launch_bounds__(256) void scan_kernel(
    const u32* __restrict__ hist, u32* __restrict__ offs,
    u32* __restrict__ cur, int B) {
    __shared__ u32 sh[256];
    const int t = threadIdx.x;
    for (int s = 0; s < 2; ++s) {
        const u32 v = (t < B) ? hist[s * B + t] : 0u;
        sh[t] = v;
        __syncthreads();
#pragma unroll
        for (int off = 1; off < 256; off <<= 1) {
            const u32 add = (t >= off) ? sh[t - off] : 0u;
            __syncthreads();
            sh[t] += add;
            __syncthreads();
        }
        const u32 exc = sh[t] - v;
        if (t < B) {
            offs[s * (B + 1) + t] = exc;
            cur[s * B + t] = exc;
        }
        if (t == 255) offs[s * (B + 1) + B] = sh[255];
        __syncthreads();
    }
}

// scatter: build bucket-sorted edge id list AND sorted rows/cols/attr copies
#define SCHUNK 4096
__global__ __launch_bounds__(256) void scatter_kernel(
    const int* __restrict__ lr, const int* __restrict__ ur,
    const int* __restrict__ lc, const int* __restrict__ uc,
    const float* __restrict__ la, const float* __restrict__ ua,
    u32* __restrict__ cur, u32* __restrict__ list,
    int* __restrict__ rs, int* __restrict__ cs, float* __restrict__ as_,
    int E, int B) {
    __shared__ u32 lcnt[256], lbase[256];
    const int t = threadIdx.x;
    const int s = blockIdx.y;
    const int* rows = s ? ur : lr;
    const int* cols = s ? uc : lc;
    const float* attr = s ? ua : la;
    u32* mylist = list + (size_t)s * E;
    int* myrs = rs + (size_t)s * E;
    int* mycs = cs + (size_t)s * E;
    float* myas = as_ + (size_t)s * E;
    if (t < B) lcnt[t] = 0;
    __syncthreads();
    const int base_e = blockIdx.x * SCHUNK;
#pragma unroll
    for (int k = 0; k < SCHUNK / 256; ++k) {
        const int e = base_e + k * 256 + t;
        if (e < E) atomicAdd(&lcnt[rows[e] >> NB_SHIFT], 1u);
    }
    __syncthreads();
    if (t < B) {
        const u32 c = lcnt[t];
        lbase[t] = c ? atomicAdd(&cur[s * B + t], c) : 0u;
        lcnt[t] = 0;
    }
    __syncthreads();
#pragma unroll
    for (int k = 0; k < SCHUNK / 256; ++k) {
        const int e = base_e + k * 256 + t;
        if (e < E) {
            const int rv = rows[e];
            const int b = rv >> NB_SHIFT;
            const u32 pos = lbase[b] + atomicAdd(&lcnt[b], 1u);
            mylist[pos] = (u32)e;
            myrs[pos] = rv;
            mycs[pos] = cols[e];
            myas[pos] = attr[e];
        }
    }
}

// ---------------- edge MLP (+ inline global MLP in wave 0) ----------------
// Sorted domain: one sorted-edge per thread; all inputs coalesced.
// k-outer with float4 weight-row loads; h[32]+in[18] register-resident.

template <bool SKIP, bool GAGG, bool VALS, bool STORE, bool GCOMP>
__global__ __launch_bounds__(256, 3) void edge_kernel(
    const float4* __restrict__ xf,       // node features (N,8) as float4 pairs
    const int* __restrict__ rows, const int* __restrict__ cols,  // sorted
    const float* __restrict__ eprev,     // previous edge embedding (sorted)
    const float* __restrict__ skipattr,  // sorted original attr, if SKIP
    const u32* __restrict__ ids,         // sorted -> original edge id (VALS)
    const float* __restrict__ W1,        // 26x32 slice (row-major k,j)
    const float* __restrict__ b1,        // 32
    const float* __restrict__ W2,        // 32
    const float* __restrict__ b2,        // 1
    const float* __restrict__ gprev,     // gslot[j-1] (GCOMP) / gslot[0]=0
    float* __restrict__ gout,            // gslot[j] (GCOMP: block0 writes)
    const float* __restrict__ pebins,    // prev region e-mean bins (GCOMP)
    const float* __restrict__ pnbins,    // prev region n-mean bins (GCOMP)
    const float* __restrict__ gW1, const float* __restrict__ gb1,
    const float* __restrict__ gW2, const float* __restrict__ gb2,
    float* __restrict__ ebins,           // this region's e-mean bins (GAGG)
    float* __restrict__ e_out,           // edge emb store, sorted (STORE)
    float* __restrict__ vals_out,        // final output segment (VALS)
    int E, int N, float inv_E) {
    __shared__ float gsh[8];
    __shared__ float biasE[32];
    __shared__ float wpart[4];
    const int t = threadIdx.x;
    if constexpr (GCOMP) {
        if (t < 64) {  // wave 0: g = gMLP(n_mean, e_mean, g_prev)
            float nb[8];
#pragma unroll
            for (int q = 0; q < 8; ++q) nb[q] = pnbins[t * 16 + q];
            const float eb = pebins[t];
            float gin[17];
#pragma unroll
            for (int q = 0; q < 8; ++q) {
                const float s = wave_sum(nb[q]);
                gin[q] = __shfl(s, 0, 64) / (float)N;
            }
            const float es = wave_sum(eb);
            gin[8] = __shfl(es, 0, 64) * inv_E;
#pragma unroll
            for (int k = 0; k < 8; ++k) gin[9 + k] = gprev[k];
            float hv = 0.0f;
            if (t < 32) {
                hv = gb1[t];
#pragma unroll
                for (int k = 0; k < 17; ++k)
                    hv = fmaf(gin[k], gW1[k * 32 + t], hv);
                hv = fmaxf(hv, 0.0f);
            }
#pragma unroll
            for (int q = 0; q < 8; ++q) {
                const float c = (t < 32) ? hv * gW2[t * 8 + q] : 0.0f;
                const float s = wave_sum(c);
                if (t == 0) {
                    const float gv = gb2[q] + s;
                    gsh[q] = gv;
                    if (blockIdx.x == 0) gout[q] = gv;
                }
            }
        }
    } else {
        if (t < 8) gsh[t] = gprev[t];
    }
    __syncthreads();
    if (t < 32) {
        // fold uniform global contribution + b1 into per-pass bias
        float v = b1[t];
#pragma unroll
        for (int k = 0; k < 8; ++k) v = fmaf(gsh[k], W1[k * 32 + t], v);
        biasE[t] = v;
    }
    __syncthreads();

    const int e = blockIdx.x * 256 + t;
    const bool valid = e < E;
    const int idx = valid ? e : 0;
    const int r = rows[idx];
    const int c = cols[idx];
    const float4 xr0 = xf[2 * r], xr1 = xf[2 * r + 1];
    const float4 xc0 = xf[2 * c], xc1 = xf[2 * c + 1];
    float in[18] = {xr0.x, xr0.y, xr0.z, xr0.w, xr1.x, xr1.y, xr1.z, xr1.w,
                    xc0.x, xc0.y, xc0.z, xc0.w, xc1.x, xc1.y, xc1.z, xc1.w,
                    eprev[idx], 0.0f};
    if constexpr (SKIP) in[17] = skipattr[idx];

    float h[32];
#pragma unroll
    for (int q = 0; q < 8; ++q) {
        const float4 b = reinterpret_cast<const float4*>(biasE)[q];
        h[4 * q + 0] = b.x; h[4 * q + 1] = b.y;
        h[4 * q + 2] = b.z; h[4 * q + 3] = b.w;
    }
    // k-outer: per k, one contiguous weight row (8 x float4) feeds 32 FMAs
    const float4* __restrict__ W4 =
        reinterpret_cast<const float4*>(W1 + 8 * 32);  // rows 8..25
#pragma unroll
    for (int k = 0; k < 18; ++k) {
        const float v = in[k];
#pragma unroll
        for (int q = 0; q < 8; ++q) {
            const float4 w = W4[k * 8 + q];
            h[4 * q + 0] = fmaf(v, w.x, h[4 * q + 0]);
            h[4 * q + 1] = fmaf(v, w.y, h[4 * q + 1]);
            h[4 * q + 2] = fmaf(v, w.z, h[4 * q + 2]);
            h[4 * q + 3] = fmaf(v, w.w, h[4 * q + 3]);
        }
    }
    float out = b2[0];
    const float4* __restrict__ W24 = reinterpret_cast<const float4*>(W2);
#pragma unroll
    for (int q = 0; q < 8; ++q) {
        const float4 w = W24[q];
        out = fmaf(fmaxf(h[4 * q + 0], 0.f), w.x, out);
        out = fmaf(fmaxf(h[4 * q + 1], 0.f), w.y, out);
        out = fmaf(fmaxf(h[4 * q + 2], 0.f), w.z, out);
        out = fmaf(fmaxf(h[4 * q + 3], 0.f), w.w, out);
    }

    if (valid) {
        if constexpr (STORE) e_out[e] = out;
        if constexpr (VALS) vals_out[ids[e]] = (r == c) ? expf(out) : out;
    }
    if constexpr (GAGG) {
        const float s = wave_sum(valid ? out : 0.0f);
        if ((t & 63) == 0) wpart[t >> 6] = s;
        __syncthreads();
        if (t == 0)
            atomicAdd(&ebins[blockIdx.x & 63],
                      wpart[0] + wpart[1] + wpart[2] + wpart[3]);
    }
}

// ------- fused aggregation + node MLP: one block owns one bucket -------
// Sorted domain: e_emb/rows reads fully coalesced (no gathers).

template <bool COUNT, bool STORE_N>
__global__ __launch_bounds__(1024) void aggnode_kernel(
    const u32* __restrict__ offs,
    const int* __restrict__ rows,       // sorted rows
    const float* __restrict__ e_emb,    // sorted edge embeddings
    const float4* __restrict__ xf,  // node features: x (lower) or l_n (upper)
    float* __restrict__ cntf,       // per-node degree (write if COUNT else read)
    const float* __restrict__ g,    // gslot[j] (materialized)
    const float* __restrict__ nW1, const float* __restrict__ nb1,
    const float* __restrict__ nW2, const float* __restrict__ nb2,
    float* __restrict__ n_out,  // l_n (8N) if STORE_N
    float* __restrict__ nbins,  // 64 x 16 n-mean partial bins
    int N) {
    __shared__ float sbin[NB_SIZE];
    __shared__ float cbin[NB_SIZE];
    __shared__ float biasN[32];
    __shared__ float npart[8][8];
    const int t = threadIdx.x;
    if (t < NB_SIZE) {
        sbin[t] = 0.0f;
        if constexpr (COUNT) cbin[t] = 0.0f;
    }
    if (t >= NB_SIZE && t < NB_SIZE + 32) {
        const int j = t - NB_SIZE;
        float v = nb1[j];
#pragma unroll
        for (int k = 0; k < 8; ++k) v = fmaf(g[k], nW1[k * 32 + j], v);
        biasN[j] = v;
    }
    __syncthreads();
    const int b = blockIdx.x;
    const u32 beg = offs[b], end = offs[b + 1];
    for (u32 i = beg + t; i < end; i += 1024) {
        const float v = e_emb[i];
        const int r = rows[i];
        atomicAdd(&sbin[r & (NB_SIZE - 1)], v);
        if constexpr (COUNT) atomicAdd(&cbin[r & (NB_SIZE - 1)], 1.0f);
    }
    __syncthreads();

    const int n0 = b << NB_SHIFT;
    float o[8];
    const bool active = (t < NB_SIZE) && (n0 + t < N);
    if (t < NB_SIZE) {
        const int n = n0 + t;
        const int idx = active ? n : (N - 1);
        float cntv;
        if constexpr (COUNT) {
            cntv = cbin[t];
            if (active) cntf[n] = cntv;
        } else {
            cntv = cntf[idx];
        }
        const float agg = sbin[t] / fmaxf(cntv, 1.0f);
        const float4 x0 = xf[2 * idx], x1 = xf[2 * idx + 1];
        float in[9] = {x0.x, x0.y, x0.z, x0.w, x1.x, x1.y, x1.z, x1.w, agg};
        float h[32];
#pragma unroll
        for (int j = 0; j < 8; ++j) {
            const float4 bb = reinterpret_cast<const float4*>(biasN)[j];
            h[4 * j + 0] = bb.x; h[4 * j + 1] = bb.y;
            h[4 * j + 2] = bb.z; h[4 * j + 3] = bb.w;
        }
        const float* __restrict__ Wk = nW1 + 8 * 32;
#pragma unroll
        for (int k = 0; k < 9; ++k) {
            const float v = in[k];
#pragma unroll
            for (int j = 0; j < 32; ++j) h[j] = fmaf(v, Wk[k * 32 + j], h[j]);
        }
#pragma unroll
        for (int q = 0; q < 8; ++q) o[q] = nb2[q];
#pragma unroll
        for (int j = 0; j < 32; ++j) {
            const float hv = fmaxf(h[j], 0.0f);
#pragma unroll
            for (int q = 0; q < 8; ++q) o[q] = fmaf(hv, nW2[j * 8 + q], o[q]);
        }
        if constexpr (STORE_N) {
            if (active) {
                reinterpret_cast<float4*>(n_out)[2 * n] =
                    make_float4(o[0], o[1], o[2], o[3]);
                reinterpret_cast<float4*>(n_out)[2 * n + 1] =
                    make_float4(o[4], o[5], o[6], o[7]);
            }
        }
#pragma unroll
        for (int q = 0; q < 8; ++q) {
            const float s = wave_sum(active ? o[q] : 0.0f);
            if ((t & 63) == 0) npart[t >> 6][q] = s;
        }
    }
    __syncthreads();
    if (t < 8) {
        float a = 0.0f;
#pragma unroll
        for (int w = 0; w < 8; ++w) a += npart[w][t];
        atomicAdd(&nbins[(b & 63) * 16 + t], a);
    }
}

extern "C" void kernel_launch(void* const* d_in, const int* in_sizes, int n_in,
                              void* d_out, int out_size, void* d_ws,
                              size_t ws_size, hipStream_t stream) {
    const float* x = (const float*)d_in[0];
    const int* l_ei = (const int*)d_in[1];
    const int* u_ei = (const int*)d_in[2];
    const float* l_attr = (const float*)d_in[3];
    const float* u_attr = (const float*)d_in[4];
    const float* eW1 = (const float*)d_in[5];
    const float* eb1 = (const float*)d_in[6];
    const float* eW2 = (const float*)d_in[7];
    const float* eb2 = (const float*)d_in[8];
    const float* nW1 = (const float*)d_in[9];
    const float* nb1 = (const float*)d_in[10];
    const float* nW2 = (const float*)d_in[11];
    const float* nb2 = (const float*)d_in[12];
    const float* gW1 = (const float*)d_in[13];
    const float* gb1 = (const float*)d_in[14];
    const float* gW2 = (const float*)d_in[15];
    const float* gb2 = (const float*)d_in[16];

    const int E = in_sizes[3];      // 1,100,000
    const int N = in_sizes[0] / 8;  // 100,000
    const int B = (N + NB_SIZE - 1) >> NB_SHIFT;  // 196 buckets

    // workspace layout (floats)
    float* ws = (float*)d_ws;
    float* l_e = ws;                      // E (sorted domain)
    float* u_e = l_e + E;                 // E (sorted domain)
    float* l_n = u_e + E;                 // 8N (float4-aligned)
    float* cnt_l = l_n + (size_t)8 * N;   // N (float degree)
    float* cnt_u = cnt_l + N;             // N
    float* gslot = cnt_u + N;             // 7 x 8 (slot j = g used by GNet j)
    u32* hist = (u32*)(gslot + 56);       // 2B
    float* dyn_all = (float*)(hist + 2 * B);    // 5 * RSTRIDE
    u32* offs = (u32*)(dyn_all + 5 * RSTRIDE);  // 2(B+1)
    u32* cur = offs + 2 * (B + 1);        // 2B
    u32* list = cur + 2 * B;              // 2E (sorted -> orig id)
    int* rs = (int*)(list + (size_t)2 * E);     // 2E sorted rows
    int* cs = rs + (size_t)2 * E;               // 2E sorted cols
    float* as_ = (float*)(cs + (size_t)2 * E);  // 2E sorted attrs

    const int* lr = l_ei;
    const int* lc = l_ei + E;
    const int* ur = u_ei;
    const int* uc = u_ei + E;
    const int eg = (E + 255) / 256;
    const int sg = (E + SCHUNK - 1) / SCHUNK;
    const float invE = 1.0f / (float)E;
    float* outL = (float*)d_out;
    float* outU = outL + E;
    const u32* offs_l = offs;
    const u32* offs_u = offs + (B + 1);

    // one memset: gslots + hist + all 5 bin regions
    hipMemsetAsync(gslot, 0, (size_t)(56 + 2 * B + 5 * RSTRIDE) * sizeof(float),
                   stream);
    hist_kernel<<<dim3(128, 2), 256, 0, stream>>>(lr, ur, hist, E, B);
    scan_kernel<<<1, 256, 0, stream>>>(hist, offs, cur, B);
    scatter_kernel<<<dim3(sg, 2), 256, 0, stream>>>(lr, ur, lc, uc, l_attr,
                                                    u_attr, cur, list, rs, cs,
                                                    as_, E, B);

    // weight-slice per GraphNet j: lower i -> i, upper i -> 3+i
    const size_t wsl[6] = {0, 3, 1, 4, 2, 5};

    for (int j = 0; j < 6; ++j) {
        const bool lower = !(j & 1);
        const size_t sl = wsl[j];
        float* ebins = dyn_all + (size_t)(j <= 4 ? j : 4) * RSTRIDE;
        float* nbins = ebins + 64;
        const float* pe = (j >= 1) ? dyn_all + (size_t)(j - 1) * RSTRIDE : nullptr;
        const float* pn = (j >= 1) ? pe + 64 : nullptr;
        const size_t psl = (j >= 1) ? wsl[j - 1] : 0;
        const float4* exf = (const float4*)(lower ? x : l_n);
        const int* rows_s = lower ? rs : rs + E;
        const int* cols_s = lower ? cs : cs + E;
        const float* attr_s = lower ? as_ : as_ + E;
        const u32* ids = lower ? list : list + E;
        const float* eprev = (j <= 1) ? attr_s : (lower ? l_e : u_e);
        float* e_out = lower ? l_e : u_e;
        const float* gprev = gslot + (size_t)(j >= 1 ? j - 1 : 0) * 8;
        float* gout = gslot + (size_t)j * 8;

#define EDGE_ARGS                                                             \
    exf, rows_s, cols_s, eprev, attr_s, ids, eW1 + sl * 832, eb1 + sl * 32,   \
        eW2 + sl * 32, eb2 + sl, gprev, gout, pe, pn, gW1 + psl * 544,        \
        gb1 + psl * 32, gW2 + psl * 256, gb2 + psl * 8, ebins, e_out,         \
        (j == 4) ? outL : outU, E, N, invE

        switch (j) {  // SKIP, GAGG, VALS, STORE, GCOMP
            case 0: edge_kernel<false, true, false, true, false>
                        <<<eg, 256, 0, stream>>>(EDGE_ARGS); break;
            case 1: edge_kernel<false, true, false, true, true>
                        <<<eg, 256, 0, stream>>>(EDGE_ARGS); break;
            case 2: edge_kernel<true, true, false, true, true>
                        <<<eg, 256, 0, stream>>>(EDGE_ARGS); break;
            case 3: edge_kernel<false, true, false, true, true>
                        <<<eg, 256, 0, stream>>>(EDGE_ARGS); break;
            case 4: edge_kernel<true, true, true, true, true>
                        <<<eg, 256, 0, stream>>>(EDGE_ARGS); break;
            case 5: edge_kernel<false, false, true, false, true>
                        <<<eg, 256, 0, stream>>>(EDGE_ARGS); break;
        }
#undef EDGE_ARGS

        if (j == 5) break;  // final upper GraphNet: edge output only

        const u32* aoffs = lower ? offs_l : offs_u;
        float* cntf = lower ? cnt_l : cnt_u;
        const float4* nxf = (const float4*)(lower ? x : l_n);

#define AGG_ARGS                                                              \
    aoffs, rows_s, e_out, nxf, cntf, gslot + (size_t)j * 8, nW1 + sl * 544,   \
        nb1 + sl * 32, nW2 + sl * 256, nb2 + sl * 8, l_n, nbins, N

        switch (j) {  // COUNT, STORE_N
            case 0: aggnode_kernel<true, true>
                        <<<B, 1024, 0, stream>>>(AGG_ARGS); break;
            case 1: aggnode_kernel<true, false>
                        <<<B, 1024, 0, stream>>>(AGG_ARGS); break;
            case 2: aggnode_kernel<false, true>
                        <<<B, 1024, 0, stream>>>(AGG_ARGS); break;
            case 3: aggnode_kernel<false, false>
                        <<<B, 1024, 0, stream>>>(AGG_ARGS); break;
            case 4: aggnode_kernel<false, true>
                        <<<B, 1024, 0, stream>>>(AGG_ARGS); break;
        }
#undef AGG_ARGS
    }
}

// Round 9
// 550.251 us; speedup vs baseline: 1.0342x; 1.0342x over previous
//
#include <hip/hip_runtime.h>

// NeuralIF GraphNet: 3 layers x (lower GraphNet, upper GraphNet).
// R1: bucketed edges + LDS-bin aggregation. R4: no fences in hot path.
// R5: fused aggnode; inline global MLP in edge wave 0. R7: 1 edge/thread.
// R8: sorted-domain edge arrays. R9: scatter writes ONE packed int4/edge
// (was 4 scattered arrays -> 175MB WRITE, 110us) + coalesced inv[] map;
// final vals written coalesced in sorted order, un-permuted by a tail
// kernel; edge kernel stores float2(emb,row_local) so aggnode is one
// coalesced float2 stream.

typedef unsigned int u32;

#define NB_SHIFT 9
#define NB_SIZE 512
#define RSTRIDE 1104  // per-GraphNet region: ebins[64] nbins[64*16] pad

__device__ __forceinline__ float wave_sum(float v) {
#pragma unroll
    for (int off = 32; off > 0; off >>= 1) v += __shfl_down(v, off, 64);
    return v;
}

// ---------------- bucketed-list build (once per call) ----------------

__global__ __launch_bounds__(256) void hist_kernel(
    const int* __restrict__ lr, const int* __restrict__ ur,
    u32* __restrict__ hist, int E, int B) {
    __shared__ u32 h[256];
    const int t = threadIdx.x;
    if (t < B) h[t] = 0;
    __syncthreads();
    const int s = blockIdx.y;
    const int* rows = s ? ur : lr;
    for (int i = blockIdx.x * 256 + t; i < E; i += gridDim.x * 256)
        atomicAdd(&h[rows[i] >> NB_SHIFT], 1u);
    __syncthreads();
    if (t < B && h[t]) atomicAdd(&hist[s * B + t], h[t]);
}

// parallel exclusive scan of both segments (B <= 256), one block
__global__ __launch_bounds__(256) void scan_kernel(
    const u32* __restrict__ hist, u32* __restrict__ offs,
    u32* __restrict__ cur, int B) {
    __shared__ u32 sh[256];
    const int t = threadIdx.x;
    for (int s = 0; s < 2; ++s) {
        const u32 v = (t < B) ? hist[s * B + t] : 0u;
        sh[t] = v;
        __syncthreads();
#pragma unroll
        for (int off = 1; off < 256; off <<= 1) {
            const u32 add = (t >= off) ? sh[t - off] : 0u;
            __syncthreads();
            sh[t] += add;
            __syncthreads();
        }
        const u32 exc = sh[t] - v;
        if (t < B) {
            offs[s * (B + 1) + t] = exc;
            cur[s * B + t] = exc;
        }
        if (t == 255) offs[s * (B + 1) + B] = sh[255];
        __syncthreads();
    }
}

// scatter: one packed int4 {row, col, attr_bits, 0} per sorted slot (single
// 16B scattered store) + coalesced inv[e] = sorted position.
#define SCHUNK 4096
__global__ __launch_bounds__(256) void scatter_kernel(
    const int* __restrict__ lr, const int* __restrict__ ur,
    const int* __restrict__ lc, const int* __restrict__ uc,
    const float* __restrict__ la, const float* __restrict__ ua,
    u32* __restrict__ cur, int4* __restrict__ pk, u32* __restrict__ inv,
    int E, int B) {
    __shared__ u32 lcnt[256], lbase[256];
    const int t = threadIdx.x;
    const int s = blockIdx.y;
    const int* rows = s ? ur : lr;
    const int* cols = s ? uc : lc;
    const float* attr = s ? ua : la;
    int4* mypk = pk + (size_t)s * E;
    u32* myinv = inv + (size_t)s * E;
    if (t < B) lcnt[t] = 0;
    __syncthreads();
    const int base_e = blockIdx.x * SCHUNK;
#pragma unroll
    for (int k = 0; k < SCHUNK / 256; ++k) {
        const int e = base_e + k * 256 + t;
        if (e < E) atomicAdd(&lcnt[rows[e] >> NB_SHIFT], 1u);
    }
    __syncthreads();
    if (t < B) {
        const u32 c = lcnt[t];
        lbase[t] = c ? atomicAdd(&cur[s * B + t], c) : 0u;
        lcnt[t] = 0;
    }
    __syncthreads();
#pragma unroll
    for (int k = 0; k < SCHUNK / 256; ++k) {
        const int e = base_e + k * 256 + t;
        if (e < E) {
            const int rv = rows[e];
            const int b = rv >> NB_SHIFT;
            const u32 pos = lbase[b] + atomicAdd(&lcnt[b], 1u);
            mypk[pos] = make_int4(rv, cols[e], __float_as_int(attr[e]), 0);
            myinv[e] = pos;
        }
    }
}

// ---------------- edge MLP (+ inline global MLP in wave 0) ----------------
// Sorted domain, one edge/thread; packed int4 input; k-outer float4 weights.

template <bool SKIP, bool GAGG, bool VALS, bool STORE, bool GCOMP, bool EPF2>
__global__ __launch_bounds__(256, 3) void edge_kernel(
    const float4* __restrict__ xf,       // node features (N,8) as float4 pairs
    const int4* __restrict__ pk,         // sorted {row, col, attr_bits, 0}
    const float2* __restrict__ eprevf2,  // prev edge emb (sorted), if EPF2
    const float* __restrict__ W1,        // 26x32 slice (row-major k,j)
    const float* __restrict__ b1,        // 32
    const float* __restrict__ W2,        // 32
    const float* __restrict__ b2,        // 1
    const float* __restrict__ gprev,     // gslot[j-1] (GCOMP) / gslot[0]=0
    float* __restrict__ gout,            // gslot[j] (GCOMP: block0 writes)
    const float* __restrict__ pebins,    // prev region e-mean bins (GCOMP)
    const float* __restrict__ pnbins,    // prev region n-mean bins (GCOMP)
    const float* __restrict__ gW1, const float* __restrict__ gb1,
    const float* __restrict__ gW2, const float* __restrict__ gb2,
    float* __restrict__ ebins,           // this region's e-mean bins (GAGG)
    float2* __restrict__ e_out,          // (emb, row_local) sorted (STORE)
    float* __restrict__ vsort,           // sorted final vals (VALS, coalesced)
    int E, int N, float inv_E) {
    __shared__ float gsh[8];
    __shared__ float biasE[32];
    __shared__ float wpart[4];
    const int t = threadIdx.x;
    if constexpr (GCOMP) {
        if (t < 64) {  // wave 0: g = gMLP(n_mean, e_mean, g_prev)
            float nb[8];
#pragma unroll
            for (int q = 0; q < 8; ++q) nb[q] = pnbins[t * 16 + q];
            const float eb = pebins[t];
            float gin[17];
#pragma unroll
            for (int q = 0; q < 8; ++q) {
                const float s = wave_sum(nb[q]);
                gin[q] = __shfl(s, 0, 64) / (float)N;
            }
            const float es = wave_sum(eb);
            gin[8] = __shfl(es, 0, 64) * inv_E;
#pragma unroll
            for (int k = 0; k < 8; ++k) gin[9 + k] = gprev[k];
            float hv = 0.0f;
            if (t < 32) {
                hv = gb1[t];
#pragma unroll
                for (int k = 0; k < 17; ++k)
                    hv = fmaf(gin[k], gW1[k * 32 + t], hv);
                hv = fmaxf(hv, 0.0f);
            }
#pragma unroll
            for (int q = 0; q < 8; ++q) {
                const float c = (t < 32) ? hv * gW2[t * 8 + q] : 0.0f;
                const float s = wave_sum(c);
                if (t == 0) {
                    const float gv = gb2[q] + s;
                    gsh[q] = gv;
                    if (blockIdx.x == 0) gout[q] = gv;
                }
            }
        }
    } else {
        if (t < 8) gsh[t] = gprev[t];
    }
    __syncthreads();
    if (t < 32) {
        // fold uniform global contribution + b1 into per-pass bias
        float v = b1[t];
#pragma unroll
        for (int k = 0; k < 8; ++k) v = fmaf(gsh[k], W1[k * 32 + t], v);
        biasE[t] = v;
    }
    __syncthreads();

    const int e = blockIdx.x * 256 + t;
    const bool valid = e < E;
    const int idx = valid ? e : 0;
    const int4 p = pk[idx];
    const int r = p.x;
    const int c = p.y;
    const float attr = __int_as_float(p.z);
    float epv;
    if constexpr (EPF2) epv = eprevf2[idx].x;
    else epv = attr;
    const float4 xr0 = xf[2 * r], xr1 = xf[2 * r + 1];
    const float4 xc0 = xf[2 * c], xc1 = xf[2 * c + 1];
    float in[18] = {xr0.x, xr0.y, xr0.z, xr0.w, xr1.x, xr1.y, xr1.z, xr1.w,
                    xc0.x, xc0.y, xc0.z, xc0.w, xc1.x, xc1.y, xc1.z, xc1.w,
                    epv, 0.0f};
    if constexpr (SKIP) in[17] = attr;

    float h[32];
#pragma unroll
    for (int q = 0; q < 8; ++q) {
        const float4 b = reinterpret_cast<const float4*>(biasE)[q];
        h[4 * q + 0] = b.x; h[4 * q + 1] = b.y;
        h[4 * q + 2] = b.z; h[4 * q + 3] = b.w;
    }
    // k-outer: per k, one contiguous weight row (8 x float4) feeds 32 FMAs
    const float4* __restrict__ W4 =
        reinterpret_cast<const float4*>(W1 + 8 * 32);  // rows 8..25
#pragma unroll
    for (int k = 0; k < 18; ++k) {
        const float v = in[k];
#pragma unroll
        for (int q = 0; q < 8; ++q) {
            const float4 w = W4[k * 8 + q];
            h[4 * q + 0] = fmaf(v, w.x, h[4 * q + 0]);
            h[4 * q + 1] = fmaf(v, w.y, h[4 * q + 1]);
            h[4 * q + 2] = fmaf(v, w.z, h[4 * q + 2]);
            h[4 * q + 3] = fmaf(v, w.w, h[4 * q + 3]);
        }
    }
    float out = b2[0];
    const float4* __restrict__ W24 = reinterpret_cast<const float4*>(W2);
#pragma unroll
    for (int q = 0; q < 8; ++q) {
        const float4 w = W24[q];
        out = fmaf(fmaxf(h[4 * q + 0], 0.f), w.x, out);
        out = fmaf(fmaxf(h[4 * q + 1], 0.f), w.y, out);
        out = fmaf(fmaxf(h[4 * q + 2], 0.f), w.z, out);
        out = fmaf(fmaxf(h[4 * q + 3], 0.f), w.w, out);
    }

    if (valid) {
        if constexpr (STORE)
            e_out[e] = make_float2(out, __int_as_float(r & (NB_SIZE - 1)));
        if constexpr (VALS) vsort[e] = (r == c) ? expf(out) : out;
    }
    if constexpr (GAGG) {
        const float s = wave_sum(valid ? out : 0.0f);
        if ((t & 63) == 0) wpart[t >> 6] = s;
        __syncthreads();
        if (t == 0)
            atomicAdd(&ebins[blockIdx.x & 63],
                      wpart[0] + wpart[1] + wpart[2] + wpart[3]);
    }
}

// ------- fused aggregation + node MLP: one block owns one bucket -------
// Single coalesced float2 stream (emb, row_local).

template <bool COUNT, bool STORE_N>
__global__ __launch_bounds__(1024) void aggnode_kernel(
    const u32* __restrict__ offs,
    const float2* __restrict__ em,  // sorted (emb, row_local)
    const float4* __restrict__ xf,  // node features: x (lower) or l_n (upper)
    float* __restrict__ cntf,       // per-node degree (write if COUNT else read)
    const float* __restrict__ g,    // gslot[j] (materialized)
    const float* __restrict__ nW1, const float* __restrict__ nb1,
    const float* __restrict__ nW2, const float* __restrict__ nb2,
    float* __restrict__ n_out,  // l_n (8N) if STORE_N
    float* __restrict__ nbins,  // 64 x 16 n-mean partial bins
    int N) {
    __shared__ float sbin[NB_SIZE];
    __shared__ float cbin[NB_SIZE];
    __shared__ float biasN[32];
    __shared__ float npart[8][8];
    const int t = threadIdx.x;
    if (t < NB_SIZE) {
        sbin[t] = 0.0f;
        if constexpr (COUNT) cbin[t] = 0.0f;
    }
    if (t >= NB_SIZE && t < NB_SIZE + 32) {
        const int j = t - NB_SIZE;
        float v = nb1[j];
#pragma unroll
        for (int k = 0; k < 8; ++k) v = fmaf(g[k], nW1[k * 32 + j], v);
        biasN[j] = v;
    }
    __syncthreads();
    const int b = blockIdx.x;
    const u32 beg = offs[b], end = offs[b + 1];
    for (u32 i = beg + t; i < end; i += 1024) {
        const float2 v = em[i];
        const int rl = __float_as_int(v.y);
        atomicAdd(&sbin[rl], v.x);
        if constexpr (COUNT) atomicAdd(&cbin[rl], 1.0f);
    }
    __syncthreads();

    const int n0 = b << NB_SHIFT;
    float o[8];
    const bool active = (t < NB_SIZE) && (n0 + t < N);
    if (t < NB_SIZE) {
        const int n = n0 + t;
        const int idx = active ? n : (N - 1);
        float cntv;
        if constexpr (COUNT) {
            cntv = cbin[t];
            if (active) cntf[n] = cntv;
        } else {
            cntv = cntf[idx];
        }
        const float agg = sbin[t] / fmaxf(cntv, 1.0f);
        const float4 x0 = xf[2 * idx], x1 = xf[2 * idx + 1];
        float in[9] = {x0.x, x0.y, x0.z, x0.w, x1.x, x1.y, x1.z, x1.w, agg};
        float h[32];
#pragma unroll
        for (int j = 0; j < 8; ++j) {
            const float4 bb = reinterpret_cast<const float4*>(biasN)[j];
            h[4 * j + 0] = bb.x; h[4 * j + 1] = bb.y;
            h[4 * j + 2] = bb.z; h[4 * j + 3] = bb.w;
        }
        const float* __restrict__ Wk = nW1 + 8 * 32;
#pragma unroll
        for (int k = 0; k < 9; ++k) {
            const float v = in[k];
#pragma unroll
            for (int j = 0; j < 32; ++j) h[j] = fmaf(v, Wk[k * 32 + j], h[j]);
        }
#pragma unroll
        for (int q = 0; q < 8; ++q) o[q] = nb2[q];
#pragma unroll
        for (int j = 0; j < 32; ++j) {
            const float hv = fmaxf(h[j], 0.0f);
#pragma unroll
            for (int q = 0; q < 8; ++q) o[q] = fmaf(hv, nW2[j * 8 + q], o[q]);
        }
        if constexpr (STORE_N) {
            if (active) {
                reinterpret_cast<float4*>(n_out)[2 * n] =
                    make_float4(o[0], o[1], o[2], o[3]);
                reinterpret_cast<float4*>(n_out)[2 * n + 1] =
                    make_float4(o[4], o[5], o[6], o[7]);
            }
        }
#pragma unroll
        for (int q = 0; q < 8; ++q) {
            const float s = wave_sum(active ? o[q] : 0.0f);
            if ((t & 63) == 0) npart[t >> 6][q] = s;
        }
    }
    __syncthreads();
    if (t < 8) {
        float a = 0.0f;
#pragma unroll
        for (int w = 0; w < 8; ++w) a += npart[w][t];
        atomicAdd(&nbins[(b & 63) * 16 + t], a);
    }
}

// -------- tail: un-permute sorted vals into original edge order --------

__global__ __launch_bounds__(256) void unperm_kernel(
    const float* __restrict__ vs,   // [2E] sorted vals (lower | upper)
    const u32* __restrict__ inv,    // [2E] orig -> sorted pos (per half)
    float* __restrict__ out, int E) {
    const int i = blockIdx.x * 256 + threadIdx.x;
    if (i < 2 * E) {
        const u32 p = inv[i];
        out[i] = (i < E) ? vs[p] : vs[E + p];
    }
}

extern "C" void kernel_launch(void* const* d_in, const int* in_sizes, int n_in,
                              void* d_out, int out_size, void* d_ws,
                              size_t ws_size, hipStream_t stream) {
    const float* x = (const float*)d_in[0];
    const int* l_ei = (const int*)d_in[1];
    const int* u_ei = (const int*)d_in[2];
    const float* l_attr = (const float*)d_in[3];
    const float* u_attr = (const float*)d_in[4];
    const float* eW1 = (const float*)d_in[5];
    const float* eb1 = (const float*)d_in[6];
    const float* eW2 = (const float*)d_in[7];
    const float* eb2 = (const float*)d_in[8];
    const float* nW1 = (const float*)d_in[9];
    const float* nb1 = (const float*)d_in[10];
    const float* nW2 = (const float*)d_in[11];
    const float* nb2 = (const float*)d_in[12];
    const float* gW1 = (const float*)d_in[13];
    const float* gb1 = (const float*)d_in[14];
    const float* gW2 = (const float*)d_in[15];
    const float* gb2 = (const float*)d_in[16];

    const int E = in_sizes[3];      // 1,100,000
    const int N = in_sizes[0] / 8;  // 100,000
    const int B = (N + NB_SIZE - 1) >> NB_SHIFT;  // 196 buckets

    // workspace layout (floats); ws_size ~256MB (fill evidence, R4 profile)
    float* ws = (float*)d_ws;
    int4* pk = (int4*)ws;                       // 2E int4 (lower | upper)
    float* l_e = ws + (size_t)8 * E;            // 2E floats (float2)
    float* u_e = l_e + (size_t)2 * E;           // 2E floats (float2)
    float* vs = u_e + (size_t)2 * E;            // 2E (vs_l | vs_u)
    u32* inv = (u32*)(vs + (size_t)2 * E);      // 2E
    float* l_n = (float*)(inv + (size_t)2 * E); // 8N (16B-aligned: 16E*4 % 16 == 0)
    float* cnt_l = l_n + (size_t)8 * N;         // N
    float* cnt_u = cnt_l + N;                   // N
    float* gslot = cnt_u + N;                   // 7 x 8  -- zeroed region start
    u32* hist = (u32*)(gslot + 56);             // 2B
    float* dyn_all = (float*)(hist + 2 * B);    // 5 * RSTRIDE
    u32* offs = (u32*)(dyn_all + 5 * RSTRIDE);  // 2(B+1)
    u32* cur = offs + 2 * (B + 1);              // 2B

    const int* lr = l_ei;
    const int* lc = l_ei + E;
    const int* ur = u_ei;
    const int* uc = u_ei + E;
    const int eg = (E + 255) / 256;
    const int sg = (E + SCHUNK - 1) / SCHUNK;
    const float invE = 1.0f / (float)E;
    float* outAll = (float*)d_out;
    const u32* offs_l = offs;
    const u32* offs_u = offs + (B + 1);

    // one memset: gslots + hist + all 5 bin regions
    hipMemsetAsync(gslot, 0, (size_t)(56 + 2 * B + 5 * RSTRIDE) * sizeof(float),
                   stream);
    hist_kernel<<<dim3(128, 2), 256, 0, stream>>>(lr, ur, hist, E, B);
    scan_kernel<<<1, 256, 0, stream>>>(hist, offs, cur, B);
    scatter_kernel<<<dim3(sg, 2), 256, 0, stream>>>(lr, ur, lc, uc, l_attr,
                                                    u_attr, cur, pk, inv, E, B);

    // weight-slice per GraphNet j: lower i -> i, upper i -> 3+i
    const size_t wsl[6] = {0, 3, 1, 4, 2, 5};

    for (int j = 0; j < 6; ++j) {
        const bool lower = !(j & 1);
        const size_t sl = wsl[j];
        float* ebins = dyn_all + (size_t)(j <= 4 ? j : 4) * RSTRIDE;
        float* nbins = ebins + 64;
        const float* pe = (j >= 1) ? dyn_all + (size_t)(j - 1) * RSTRIDE : nullptr;
        const float* pn = (j >= 1) ? pe + 64 : nullptr;
        const size_t psl = (j >= 1) ? wsl[j - 1] : 0;
        const float4* exf = (const float4*)(lower ? x : l_n);
        const int4* pks = lower ? pk : pk + E;
        const float2* eprevf2 =
            (const float2*)(lower ? l_e : u_e);  // used when EPF2
        float2* e_out = (float2*)(lower ? l_e : u_e);
        float* vsort = lower ? vs : vs + E;
        const float* gprev = gslot + (size_t)(j >= 1 ? j - 1 : 0) * 8;
        float* gout = gslot + (size_t)j * 8;

#define EDGE_ARGS                                                             \
    exf, pks, eprevf2, eW1 + sl * 832, eb1 + sl * 32, eW2 + sl * 32,          \
        eb2 + sl, gprev, gout, pe, pn, gW1 + psl * 544, gb1 + psl * 32,       \
        gW2 + psl * 256, gb2 + psl * 8, ebins, e_out, vsort, E, N, invE

        switch (j) {  // SKIP, GAGG, VALS, STORE, GCOMP, EPF2
            case 0: edge_kernel<false, true, false, true, false, false>
                        <<<eg, 256, 0, stream>>>(EDGE_ARGS); break;
            case 1: edge_kernel<false, true, false, true, true, false>
                        <<<eg, 256, 0, stream>>>(EDGE_ARGS); break;
            case 2: edge_kernel<true, true, false, true, true, true>
                        <<<eg, 256, 0, stream>>>(EDGE_ARGS); break;
            case 3: edge_kernel<false, true, false, true, true, true>
                        <<<eg, 256, 0, stream>>>(EDGE_ARGS); break;
            case 4: edge_kernel<true, true, true, true, true, true>
                        <<<eg, 256, 0, stream>>>(EDGE_ARGS); break;
            case 5: edge_kernel<false, false, true, false, true, true>
                        <<<eg, 256, 0, stream>>>(EDGE_ARGS); break;
        }
#undef EDGE_ARGS

        if (j == 5) break;  // final upper GraphNet: edge output only

        const u32* aoffs = lower ? offs_l : offs_u;
        float* cntf = lower ? cnt_l : cnt_u;
        const float4* nxf = (const float4*)(lower ? x : l_n);
        const float2* em = (const float2*)(lower ? l_e : u_e);

#define AGG_ARGS                                                              \
    aoffs, em, nxf, cntf, gslot + (size_t)j * 8, nW1 + sl * 544,              \
        nb1 + sl * 32, nW2 + sl * 256, nb2 + sl * 8, l_n, nbins, N

        switch (j) {  // COUNT, STORE_N
            case 0: aggnode_kernel<true, true>
                        <<<B, 1024, 0, stream>>>(AGG_ARGS); break;
            case 1: aggnode_kernel<true, false>
                        <<<B, 1024, 0, stream>>>(AGG_ARGS); break;
            case 2: aggnode_kernel<false, true>
                        <<<B, 1024, 0, stream>>>(AGG_ARGS); break;
            case 3: aggnode_kernel<false, false>
                        <<<B, 1024, 0, stream>>>(AGG_ARGS); break;
            case 4: aggnode_kernel<false, true>
                        <<<B, 1024, 0, stream>>>(AGG_ARGS); break;
        }
#undef AGG_ARGS
    }

    unperm_kernel<<<(2 * E + 255) / 256, 256, 0, stream>>>(vs, inv, outAll, E);
}